// Round 3
// baseline (461.447 us; speedup 1.0000x reference)
//
#include <hip/hip_runtime.h>
#include <stdint.h>

#define CATS  32
#define DI    1024
#define DO    1024
#define NB    64
#define ST    512

#define BM 256
#define BN 128
#define BK 64
#define NSTEP (DI / BK)                         // 16
#define NBLK  (NB * (ST / BM) * (DO / BN))      // 64*2*8 = 1024

typedef float  f32x4  __attribute__((ext_vector_type(4)));
typedef float  f32x2  __attribute__((ext_vector_type(2)));
typedef short  bf16x8 __attribute__((ext_vector_type(8)));

// v_cvt_pk_bf16_f32: lo -> D[15:0], hi -> D[31:16], RNE (matches reference path).
__device__ __forceinline__ uint32_t cvt_pk_bf16(float lo, float hi) {
    uint32_t r;
    asm("v_cvt_pk_bf16_f32 %0, %1, %2" : "=v"(r) : "v"(lo), "v"(hi));
    return r;
}

// Fused per-category GEMM, fp32 in/out, bf16 MFMA internally.
//
// Geometry: 256(m) x 128(n) tile, BK=64, 512 thr = 8 waves (4m x 2n),
// per-wave 64x64 output (acc[4][4] f32x4 = 64 regs). LDS 96 KB, dbuf.
//
// LDS layout (A and B): element (row,k) lives at ushort index
//   row*64 + c*8 + (k&7),  c = (k>>3) ^ (row&7) ^ ((row>>3)&7)
// Hand-checked bank behavior: A-write b128, B-write b128, A-frag b128,
// B-frag b128 all <=2-way (free). Fragment-read lane mapping, MFMA call
// shape, and epilogue are identical to the previously verified kernel.
__global__ __launch_bounds__(512, 2) void fused_cat_gemm_kernel(
        const float* __restrict__ x, const int* __restrict__ cat_ids,
        const float* __restrict__ W, const float* __restrict__ bias,
        float* __restrict__ out) {
    __shared__ __align__(16) unsigned short As[2][BM * BK];  // 2 x 32 KB
    __shared__ __align__(16) unsigned short Bs[2][BN * BK];  // 2 x 16 KB

    // XCD-aware remap (bijective, 1024 = 8*128): each XCD owns 8 whole batch
    // elements -> x-slab + W[cat] panels L2/LLC-local.
    const int fb = blockIdx.x;
    const int vv = (fb & 7) * 128 + (fb >> 3);
    const int b     = vv >> 4;                 // 16 blocks per batch element
    const int mbase = ((vv >> 3) & 1) * BM;    // 2 m-tiles
    const int nbase = (vv & 7) * BN;           // 8 n-tiles (fastest: share A)
    const int cat   = cat_ids[b];

    const int tid  = threadIdx.x;
    const int lane = tid & 63;
    const int w    = tid >> 6;     // 0..7
    const int wr   = w >> 1;       // 0..3 : m quarter (64 rows)
    const int wc   = w & 1;        // 0..1 : n half (64 cols)
    const int l15  = lane & 15;
    const int kg   = lane >> 4;

    // ---- A staging: thread = (row, k-half). 8x f32x4 loads (32 contiguous
    // floats of one x row), 16 cvt_pk, 4x ds_write_b128.
    const int arow = tid >> 1;            // 0..255
    const int ah   = tid & 1;             // k half (32 floats)
    const int axr  = (arow & 7) ^ ((arow >> 3) & 7);
    const float* gA = x + (size_t)(b * ST + mbase + arow) * DI + ah * 32;

    // ---- B staging: thread = (n-pair, 8k-chunk). 8x f32x2 loads (8 k-rows
    // of W at one n-pair; wave = 512 B contiguous per row), 8 cvt_pk packing
    // k-pairs, 2x ds_write_b128 (transpose happens in the write addressing).
    const int np  = tid & 63;             // n-pair: n = 2*np, 2*np+1
    const int kc8 = tid >> 6;             // 0..7: k-chunk of 8
    int bxr[2];
    #pragma unroll
    for (int j = 0; j < 2; ++j) {
        const int nr = np * 2 + j;
        bxr[j] = (nr & 7) ^ ((nr >> 3) & 7);
    }
    const float* gB = W + ((size_t)cat * DI + kc8 * 8) * DO + nbase + np * 2;

    // ---- fragment read offsets (ushort units); kk toggles chunk bit2 -> ^32
    int offA[4], offB[4];
    #pragma unroll
    for (int mi = 0; mi < 4; ++mi) {
        const int row = wr * 64 + mi * 16 + l15;
        const int rx  = (l15 & 7) ^ ((2 * mi + (l15 >> 3)) & 7);
        offA[mi] = row * BK + ((kg ^ rx) * 8);
    }
    #pragma unroll
    for (int ni = 0; ni < 4; ++ni) {
        const int row = wc * 64 + ni * 16 + l15;
        const int rx  = (l15 & 7) ^ ((2 * ni + (l15 >> 3)) & 7);
        offB[ni] = row * BK + ((kg ^ rx) * 8);
    }

    f32x4 acc[4][4];
    #pragma unroll
    for (int mi = 0; mi < 4; ++mi)
        #pragma unroll
        for (int ni = 0; ni < 4; ++ni)
            acc[mi][ni] = (f32x4){0.f, 0.f, 0.f, 0.f};

    f32x4 ra[8];
    f32x2 rb[8];

    auto LOADS_A = [&](int s) {
        #pragma unroll
        for (int q = 0; q < 8; ++q)
            ra[q] = *(const f32x4*)(gA + (size_t)s * BK + q * 4);
    };
    auto LOADS_B = [&](int s) {
        #pragma unroll
        for (int q = 0; q < 8; ++q)
            rb[q] = *(const f32x2*)(gB + (size_t)(s * BK + q) * DO);
    };
    auto WRITES_A = [&](int bufi) {
        #pragma unroll
        for (int j = 0; j < 4; ++j) {
            const int c = (ah * 4 + j) ^ axr;
            uint4 pk;
            pk.x = cvt_pk_bf16(ra[2 * j][0], ra[2 * j][1]);
            pk.y = cvt_pk_bf16(ra[2 * j][2], ra[2 * j][3]);
            pk.z = cvt_pk_bf16(ra[2 * j + 1][0], ra[2 * j + 1][1]);
            pk.w = cvt_pk_bf16(ra[2 * j + 1][2], ra[2 * j + 1][3]);
            *(uint4*)&As[bufi][arow * BK + c * 8] = pk;
        }
    };
    auto WRITES_B = [&](int bufi) {
        #pragma unroll
        for (int j = 0; j < 2; ++j) {
            const int nrow = np * 2 + j;
            const int c    = kc8 ^ bxr[j];
            uint4 pk;
            pk.x = cvt_pk_bf16(rb[0][j], rb[1][j]);
            pk.y = cvt_pk_bf16(rb[2][j], rb[3][j]);
            pk.z = cvt_pk_bf16(rb[4][j], rb[5][j]);
            pk.w = cvt_pk_bf16(rb[6][j], rb[7][j]);
            *(uint4*)&Bs[bufi][nrow * BK + c * 8] = pk;
        }
    };
    auto COMPUTE = [&](int bufc, int kk) {
        bf16x8 af[4], bfv[4];
        #pragma unroll
        for (int ni = 0; ni < 4; ++ni)
            bfv[ni] = *(const bf16x8*)&Bs[bufc][offB[ni] ^ (kk * 32)];
        #pragma unroll
        for (int mi = 0; mi < 4; ++mi)
            af[mi] = *(const bf16x8*)&As[bufc][offA[mi] ^ (kk * 32)];
        __builtin_amdgcn_s_setprio(1);
        #pragma unroll
        for (int mi = 0; mi < 4; ++mi)
            #pragma unroll
            for (int ni = 0; ni < 4; ++ni)
                acc[mi][ni] = __builtin_amdgcn_mfma_f32_16x16x32_bf16(
                                  af[mi], bfv[ni], acc[mi][ni], 0, 0, 0);
        __builtin_amdgcn_s_setprio(0);
    };

    #define LGKM_BARRIER()                                      \
        do {                                                    \
            asm volatile("s_waitcnt lgkmcnt(0)" ::: "memory");  \
            __builtin_amdgcn_s_barrier();                       \
        } while (0)

    // Prologue: tile 0 -> LDS buffer 0.
    LOADS_A(0);
    LOADS_B(0);
    WRITES_A(0);
    WRITES_B(0);
    LGKM_BARRIER();

    // Per step: loads for s+1 issue at phase top / after kk0 MFMAs; their
    // cvt+ds_writes land late (vmcnt hides under the MFMA clusters). One
    // lgkm-only barrier per step; no vmem crosses barriers.
    auto STEP = [&](int s, int bufc, bool pre) {
        if (pre) LOADS_A(s + 1);
        COMPUTE(bufc, 0);
        if (pre) LOADS_B(s + 1);
        if (pre) WRITES_A(bufc ^ 1);
        COMPUTE(bufc, 1);
        if (pre) WRITES_B(bufc ^ 1);
        LGKM_BARRIER();
    };

    #pragma unroll 1
    for (int s = 0; s < NSTEP; s += 2) {
        STEP(s, 0, true);
        STEP(s + 1, 1, s + 2 < NSTEP);
    }
    #undef LGKM_BARRIER

    // Epilogue (verified): D col = l15 (n), row = kg*4 + r (m).
    float bsv[4];
    #pragma unroll
    for (int ni = 0; ni < 4; ++ni)
        bsv[ni] = bias[(size_t)cat * DO + nbase + wc * 64 + ni * 16 + l15];

    #pragma unroll
    for (int mi = 0; mi < 4; ++mi) {
        const int rowb = mbase + wr * 64 + mi * 16 + kg * 4;
        #pragma unroll
        for (int r = 0; r < 4; ++r) {
            float* orow = out + (size_t)(b * ST + rowb + r) * DO
                              + nbase + wc * 64 + l15;
            #pragma unroll
            for (int ni = 0; ni < 4; ++ni)
                orow[ni * 16] = acc[mi][ni][r] + bsv[ni];
        }
    }
}

extern "C" void kernel_launch(void* const* d_in, const int* in_sizes, int n_in,
                              void* d_out, int out_size, void* d_ws, size_t ws_size,
                              hipStream_t stream) {
    const float* x    = (const float*)d_in[0];
    const int*   cats = (const int*)d_in[1];
    const float* W    = (const float*)d_in[2];
    const float* bias = (const float*)d_in[3];
    float*       out  = (float*)d_out;

    (void)d_ws; (void)ws_size;  // fully fused single pass, no workspace

    fused_cat_gemm_kernel<<<NBLK, 512, 0, stream>>>(x, cats, W, bias, out);
}